// Round 8
// baseline (431.440 us; speedup 1.0000x reference)
//
#include <hip/hip_runtime.h>
#include <cstddef>
#include <cstdint>

// Problem constants: B=4, N=512, FD=AD=256, PD=128, DP=64
// out[b,q] = softmax_k( (Q[b,q]·K[b,k] + bias[b,q,k]) / 16 ) · vsum[b,k]
//   bias[b,i,j] = rn*(dot(D[b,i,j,:],gw) - mu*sum_gw) + bconst (gw = g_p*(W_pt@W_ph))
//   vsum[b,k]   = Fn[b,k,:]·rowsum(Wv)
//
// Workspace layout (floats):
#define OFF_GW    0          // 64   : g_p * (W_pt @ W_ph)
#define OFF_WV    64         // 256  : row sums of Wv
#define OFF_SC    320        // 2    : sum_gw, bconst
#define OFF_VSUM  384        // 2048 : vsum[b,k]
#define OFF_Q     2432       // 524288 : Q [2048][256] row-major
#define OFF_KT    526720     // 524288 : K^T [4][256][512]  (Kt[b][f][k])
#define OFF_BIAS  1051008    // 1048576 : bias/16 [4][512][512] (entry-linear)

typedef float v4f __attribute__((ext_vector_type(4)));
typedef float v2f __attribute__((ext_vector_type(2)));

// ---------------- K0: constants -------------------------------------------
__global__ __launch_bounds__(256) void k0_consts(
    const float* __restrict__ Wv, const float* __restrict__ g_p,
    const float* __restrict__ b_p, const float* __restrict__ W_pt,
    const float* __restrict__ b_pt, const float* __restrict__ W_ph,
    float* __restrict__ ws) {
  int t = threadIdx.x;
  if (blockIdx.x < 64) {
    int row = blockIdx.x * 4 + (t >> 6);
    int l = t & 63;
    float s = 0.f;
#pragma unroll
    for (int j = 0; j < 4; ++j) s += Wv[row * 256 + l + 64 * j];
    for (int m = 32; m >= 1; m >>= 1) s += __shfl_xor(s, m);
    if (l == 0) ws[OFF_WV + row] = s;
  } else {
    __shared__ float wc_s[64];
    __shared__ float wph_s[128];
    if (t < 128) wph_s[t] = W_ph[t];
    __syncthreads();
    int c = t >> 2, sub = t & 3;
    float wc = 0.f;
#pragma unroll
    for (int j = 0; j < 32; ++j)
      wc += W_pt[c * 128 + sub * 32 + j] * wph_s[sub * 32 + j];
    wc += __shfl_xor(wc, 1);
    wc += __shfl_xor(wc, 2);
    if (sub == 0) {
      wc_s[c] = wc;
      ws[OFF_GW + c] = g_p[c] * wc;
    }
    __syncthreads();
    if (t == 0) {
      float sg = 0.f, bc = 0.f;
      for (int cc = 0; cc < 64; ++cc) {
        sg += g_p[cc] * wc_s[cc];
        bc += b_p[cc] * wc_s[cc];
      }
      for (int p = 0; p < 128; ++p) bc += b_pt[p] * wph_s[p];
      ws[OFF_SC] = sg;
      ws[OFF_SC + 1] = bc;
    }
  }
}

// ---------------- K1: LN(F) + Q,K^T projection + vsum (R6-proven) ----------
__global__ __launch_bounds__(256) void k1_ln_qk(
    const float* __restrict__ F, const float* __restrict__ Wq,
    const float* __restrict__ Wk, const float* __restrict__ g_f,
    const float* __restrict__ b_f, float* __restrict__ ws) {
  __shared__ __align__(16) float fn[8][260];
  __shared__ float smu[8], srn[8];
  int t = threadIdx.x;
  int g = blockIdx.x >> 1, h = blockIdx.x & 1;
  int row0 = g * 8;
  const float* Fp = F + (size_t)row0 * 256;
#pragma unroll
  for (int k = 0; k < 8; ++k) fn[k][t] = Fp[k * 256 + t];
  __syncthreads();
  int r = t >> 5, l32 = t & 31;
  float s1 = 0.f, s2 = 0.f;
#pragma unroll
  for (int m = 0; m < 8; ++m) {
    float x = fn[r][l32 + 32 * m];
    s1 += x;
    s2 += x * x;
  }
  for (int m = 16; m >= 1; m >>= 1) {
    s1 += __shfl_xor(s1, m);
    s2 += __shfl_xor(s2, m);
  }
  if (l32 == 0) {
    float mu = s1 * (1.f / 256.f);
    float var = s2 * (1.f / 256.f) - mu * mu;
    smu[r] = mu;
    srn[r] = rsqrtf(var + 1e-3f);
  }
  __syncthreads();
  float gf = g_f[t], bf = b_f[t];
#pragma unroll
  for (int k = 0; k < 8; ++k)
    fn[k][t] = (fn[k][t] - smu[k]) * srn[k] * gf + bf;
  __syncthreads();
  if (h == 0) {
    const float* wv = ws + OFF_WV;
    float s = 0.f;
#pragma unroll
    for (int m = 0; m < 8; ++m) s += fn[r][l32 + 32 * m] * wv[l32 + 32 * m];
    for (int m = 16; m >= 1; m >>= 1) s += __shfl_xor(s, m);
    if (l32 == 0) ws[OFF_VSUM + row0 + r] = s;
  }
  int matsel = t >> 7;  // wave-uniform: waves 0,1 -> Q, waves 2,3 -> K
  int col = h * 128 + (t & 127);
  const float* W = matsel ? Wk : Wq;
  float acc[8] = {0, 0, 0, 0, 0, 0, 0, 0};
#pragma unroll 2
  for (int f = 0; f < 256; f += 4) {
    float w0 = W[(f + 0) * 256 + col];
    float w1 = W[(f + 1) * 256 + col];
    float w2 = W[(f + 2) * 256 + col];
    float w3 = W[(f + 3) * 256 + col];
#pragma unroll
    for (int k = 0; k < 8; ++k) {
      v4f x = *(const v4f*)(&fn[k][f]);
      acc[k] = fmaf(x.w, w3,
               fmaf(x.z, w2, fmaf(x.y, w1, fmaf(x.x, w0, acc[k]))));
    }
  }
  if (matsel == 0) {
    float* Out = ws + OFF_Q + (size_t)row0 * 256 + col;
#pragma unroll
    for (int k = 0; k < 8; ++k) Out[k * 256] = acc[k];
  } else {
    int bb = row0 >> 9, r0b = row0 & 511;
    float* Out = ws + OFF_KT + (size_t)bb * 131072 + (size_t)col * 512 + r0b;
    v4f o0 = {acc[0], acc[1], acc[2], acc[3]};
    v4f o1 = {acc[4], acc[5], acc[6], acc[7]};
    *(v4f*)Out = o0;
    *(v4f*)(Out + 4) = o1;
  }
}

// ---------------- KB1: high-occupancy streaming bias pass ------------------
// 4096 blocks x 256 threads, one thread per D-entry (64 contiguous floats).
// Same proven per-lane 16x dwordx4 pattern as R6 Phase A, but at 16 waves/CU
// (__launch_bounds__(256,4); gw in LDS keeps VGPR <= 128) and 16 blocks/CU
// of grid parallelism instead of 2. Writes bias/16 coalesced (1 float/entry).
__global__ __launch_bounds__(256, 4) void kb1_bias(
    const float* __restrict__ D, float* __restrict__ ws) {
  __shared__ __align__(16) float gws[64];
  int t = threadIdx.x;
  if (t < 64) gws[t] = ws[OFF_GW + t];
  float sum_gw = ws[OFF_SC];
  float bconst = ws[OFF_SC + 1];
  __syncthreads();

  int e = blockIdx.x * 256 + t;  // entry index in [0, 4*512*512)
  const v4f* ep = (const v4f*)(D + (size_t)e * 64);
  v4f x[16];
#pragma unroll
  for (int p = 0; p < 16; ++p) x[p] = ep[p];  // 16 dwordx4 in flight
  float s1 = 0.f, s2 = 0.f, sw = 0.f;
#pragma unroll
  for (int p = 0; p < 16; ++p) {
    v4f xx = x[p];
    v4f gv = *(const v4f*)(&gws[p * 4]);  // LDS broadcast, conflict-free
    s1 += xx.x + xx.y + xx.z + xx.w;
    s2 += xx.x * xx.x + xx.y * xx.y + xx.z * xx.z + xx.w * xx.w;
    sw += xx.x * gv.x + xx.y * gv.y + xx.z * gv.z + xx.w * gv.w;
  }
  float mu = s1 * (1.f / 64.f);
  float var = s2 * (1.f / 64.f) - mu * mu;
  float rn = rsqrtf(var + 1e-3f);
  ws[OFF_BIAS + e] = (rn * (sw - mu * sum_gw) + bconst) * 0.0625f;
}

// ---------------- KB2: bias load + coalesced QK^T (R6) + softmax -----------
// 512 blocks x 256 threads. Wave w owns q-row w. Phase A replaced by a
// coalesced 8 KB bias read (rows are entry-contiguous in OFF_BIAS).
__global__ __launch_bounds__(256) void kb2_attn(
    const float* __restrict__ ws, float* __restrict__ out) {
  __shared__ float Sx[4][512];
  __shared__ __align__(16) float Qs[4][256];
  __shared__ float vs[512];
  int t = threadIdx.x;
  int w = t >> 6, l = t & 63;
  int b = blockIdx.x >> 7, tile = blockIdx.x & 127;
  int rowbase = b * 512 + tile * 4;

  // stage Q rows, vsum, bias rows (all ordered by the barrier below)
#pragma unroll
  for (int k = 0; k < 4; ++k)
    Qs[k][t] = ws[OFF_Q + (size_t)(rowbase + k) * 256 + t];
  vs[t] = ws[OFF_VSUM + b * 512 + t];
  vs[t + 256] = ws[OFF_VSUM + b * 512 + 256 + t];
  const float* bb = ws + OFF_BIAS + (size_t)rowbase * 512;
#pragma unroll
  for (int rr = 0; rr < 4; ++rr) {
    Sx[rr][t] = bb[rr * 512 + t];
    Sx[rr][t + 256] = bb[rr * 512 + 256 + t];
  }
  __syncthreads();

  // ---- Phase B: QK^T/16 added into Sx. Thread t owns k-cols 2t, 2t+1 -----
  const float* Ktb = ws + OFF_KT + (size_t)b * 131072;
  float a0[4] = {0, 0, 0, 0}, a1[4] = {0, 0, 0, 0};
#pragma unroll 2
  for (int f4 = 0; f4 < 64; ++f4) {
    v4f qv0 = *(const v4f*)(&Qs[0][f4 * 4]);  // wave-uniform broadcast
    v4f qv1 = *(const v4f*)(&Qs[1][f4 * 4]);
    v4f qv2 = *(const v4f*)(&Qs[2][f4 * 4]);
    v4f qv3 = *(const v4f*)(&Qs[3][f4 * 4]);
#pragma unroll
    for (int ff = 0; ff < 4; ++ff) {
      v2f kv = *(const v2f*)(Ktb + (size_t)(f4 * 4 + ff) * 512 + 2 * t);
      a0[0] += qv0[ff] * kv.x; a1[0] += qv0[ff] * kv.y;
      a0[1] += qv1[ff] * kv.x; a1[1] += qv1[ff] * kv.y;
      a0[2] += qv2[ff] * kv.x; a1[2] += qv2[ff] * kv.y;
      a0[3] += qv3[ff] * kv.x; a1[3] += qv3[ff] * kv.y;
    }
  }
#pragma unroll
  for (int rr = 0; rr < 4; ++rr) {
    Sx[rr][2 * t]     += a0[rr] * 0.0625f;
    Sx[rr][2 * t + 1] += a1[rr] * 0.0625f;
  }
  __syncthreads();

  // ---- Phase C: wave w softmaxes row w and dots with vsum ----
  float m = -1e30f;
#pragma unroll
  for (int j = 0; j < 8; ++j) m = fmaxf(m, Sx[w][l + 64 * j]);
  for (int mm = 32; mm >= 1; mm >>= 1) m = fmaxf(m, __shfl_xor(m, mm));
  float se = 0.f, sv = 0.f;
#pragma unroll
  for (int j = 0; j < 8; ++j) {
    float ev = __expf(Sx[w][l + 64 * j] - m);
    se += ev;
    sv += ev * vs[l + 64 * j];
  }
  for (int mm = 32; mm >= 1; mm >>= 1) {
    se += __shfl_xor(se, mm);
    sv += __shfl_xor(sv, mm);
  }
  if (l == 0) out[rowbase + w] = sv / se;
}

// ---------------------------------------------------------------------------
extern "C" void kernel_launch(void* const* d_in, const int* in_sizes, int n_in,
                              void* d_out, int out_size, void* d_ws,
                              size_t ws_size, hipStream_t stream) {
  const float* F    = (const float*)d_in[0];
  const float* D    = (const float*)d_in[1];
  const float* Wq   = (const float*)d_in[2];
  const float* Wk   = (const float*)d_in[3];
  const float* Wv   = (const float*)d_in[4];
  const float* g_f  = (const float*)d_in[5];
  const float* b_f  = (const float*)d_in[6];
  const float* g_p  = (const float*)d_in[7];
  const float* b_p  = (const float*)d_in[8];
  const float* W_pt = (const float*)d_in[9];
  const float* b_pt = (const float*)d_in[10];
  const float* W_ph = (const float*)d_in[11];
  float* out = (float*)d_out;
  float* ws = (float*)d_ws;

  k0_consts<<<65, 256, 0, stream>>>(Wv, g_p, b_p, W_pt, b_pt, W_ph, ws);
  kb1_bias<<<4096, 256, 0, stream>>>(D, ws);
  k1_ln_qk<<<512, 256, 0, stream>>>(F, Wq, Wk, g_f, b_f, ws);
  kb2_attn<<<512, 256, 0, stream>>>(ws, out);
}

// Round 11
// 411.399 us; speedup vs baseline: 1.0487x; 1.0487x over previous
//
#include <hip/hip_runtime.h>
#include <cstddef>
#include <cstdint>

// Problem constants: B=4, N=512, FD=AD=256, PD=128, DP=64
// out[b,q] = softmax_k( (Q[b,q]·K[b,k] + bias[b,q,k]) / 16 ) · vsum[b,k]
//   bias[b,i,j] = rn*(dot(D[b,i,j,:],gw) - mu*sum_gw) + bconst (gw = g_p*(W_pt@W_ph))
//   vsum[b,k]   = Fn[b,k,:]·rowsum(Wv)
//
// Workspace layout (floats):
#define OFF_GW    0          // 64   : g_p * (W_pt @ W_ph)
#define OFF_WV    64         // 256  : row sums of Wv
#define OFF_SC    320        // 2    : sum_gw, bconst
#define OFF_VSUM  384        // 2048 : vsum[b,k]
#define OFF_Q     2432       // 524288 : Q [2048][256] row-major
#define OFF_KT    526720     // 524288 : K^T [4][256][512]  (Kt[b][f][k])
#define OFF_BIAS  1051008    // 1048576 : bias/16 [4][512][512] (entry-linear)

typedef float v4f __attribute__((ext_vector_type(4)));
typedef float v2f __attribute__((ext_vector_type(2)));

// ---------------- K0: constants -------------------------------------------
__global__ __launch_bounds__(256) void k0_consts(
    const float* __restrict__ Wv, const float* __restrict__ g_p,
    const float* __restrict__ b_p, const float* __restrict__ W_pt,
    const float* __restrict__ b_pt, const float* __restrict__ W_ph,
    float* __restrict__ ws) {
  int t = threadIdx.x;
  if (blockIdx.x < 64) {
    int row = blockIdx.x * 4 + (t >> 6);
    int l = t & 63;
    float s = 0.f;
#pragma unroll
    for (int j = 0; j < 4; ++j) s += Wv[row * 256 + l + 64 * j];
    for (int m = 32; m >= 1; m >>= 1) s += __shfl_xor(s, m);
    if (l == 0) ws[OFF_WV + row] = s;
  } else {
    __shared__ float wc_s[64];
    __shared__ float wph_s[128];
    if (t < 128) wph_s[t] = W_ph[t];
    __syncthreads();
    int c = t >> 2, sub = t & 3;
    float wc = 0.f;
#pragma unroll
    for (int j = 0; j < 32; ++j)
      wc += W_pt[c * 128 + sub * 32 + j] * wph_s[sub * 32 + j];
    wc += __shfl_xor(wc, 1);
    wc += __shfl_xor(wc, 2);
    if (sub == 0) {
      wc_s[c] = wc;
      ws[OFF_GW + c] = g_p[c] * wc;
    }
    __syncthreads();
    if (t == 0) {
      float sg = 0.f, bc = 0.f;
      for (int cc = 0; cc < 64; ++cc) {
        sg += g_p[cc] * wc_s[cc];
        bc += b_p[cc] * wc_s[cc];
      }
      for (int p = 0; p < 128; ++p) bc += b_pt[p] * wph_s[p];
      ws[OFF_SC] = sg;
      ws[OFF_SC + 1] = bc;
    }
  }
}

// ---------------- KF: fused [k1-projection | bias-stream] ------------------
// 4608 blocks x 256 threads, __launch_bounds__(256,4) -> up to 4 blocks/CU.
// Blocks 0..511: R8's k1 verbatim (LN(F) + Q,K^T projection + vsum) —
//   VALU/LDS-heavy, dispatched FIRST so they are resident from t=0.
// Blocks 512..4607: R8's kb1 verbatim (per-entry pair-bias stream of D) —
//   HBM-heavy. The two populations co-schedule on each CU (MFMA/VALU vs
//   VMEM pipes are independent; m114: time ~ max, not sum), hiding the
//   entire k1 cost under the 256-MiB D stream. Also saves one launch.
__global__ __launch_bounds__(256, 4) void kf_proj_bias(
    const float* __restrict__ F, const float* __restrict__ Wq,
    const float* __restrict__ Wk, const float* __restrict__ g_f,
    const float* __restrict__ b_f, const float* __restrict__ D,
    float* __restrict__ ws) {
  __shared__ __align__(16) float fn[8][260];
  __shared__ float smu[8], srn[8];
  __shared__ __align__(16) float gws[64];
  int t = threadIdx.x;

  if (blockIdx.x >= 512) {
    // ---- bias path (R8 kb1, verified) ------------------------------------
    if (t < 64) gws[t] = ws[OFF_GW + t];
    float sum_gw = ws[OFF_SC];
    float bconst = ws[OFF_SC + 1];
    __syncthreads();

    int e = (blockIdx.x - 512) * 256 + t;  // entry index in [0, 4*512*512)
    const v4f* ep = (const v4f*)(D + (size_t)e * 64);
    v4f x[16];
#pragma unroll
    for (int p = 0; p < 16; ++p) x[p] = ep[p];  // 16 dwordx4 in flight
    float s1 = 0.f, s2 = 0.f, sw = 0.f;
#pragma unroll
    for (int p = 0; p < 16; ++p) {
      v4f xx = x[p];
      v4f gv = *(const v4f*)(&gws[p * 4]);  // LDS broadcast, conflict-free
      s1 += xx.x + xx.y + xx.z + xx.w;
      s2 += xx.x * xx.x + xx.y * xx.y + xx.z * xx.z + xx.w * xx.w;
      sw += xx.x * gv.x + xx.y * gv.y + xx.z * gv.z + xx.w * gv.w;
    }
    float mu = s1 * (1.f / 64.f);
    float var = s2 * (1.f / 64.f) - mu * mu;
    float rn = rsqrtf(var + 1e-3f);
    ws[OFF_BIAS + e] = (rn * (sw - mu * sum_gw) + bconst) * 0.0625f;
    return;
  }

  // ---- k1 path (R8 k1, verified) -----------------------------------------
  int g = blockIdx.x >> 1, h = blockIdx.x & 1;
  int row0 = g * 8;
  const float* Fp = F + (size_t)row0 * 256;
#pragma unroll
  for (int k = 0; k < 8; ++k) fn[k][t] = Fp[k * 256 + t];
  __syncthreads();
  int r = t >> 5, l32 = t & 31;
  float s1 = 0.f, s2 = 0.f;
#pragma unroll
  for (int m = 0; m < 8; ++m) {
    float x = fn[r][l32 + 32 * m];
    s1 += x;
    s2 += x * x;
  }
  for (int m = 16; m >= 1; m >>= 1) {
    s1 += __shfl_xor(s1, m);
    s2 += __shfl_xor(s2, m);
  }
  if (l32 == 0) {
    float mu = s1 * (1.f / 256.f);
    float var = s2 * (1.f / 256.f) - mu * mu;
    smu[r] = mu;
    srn[r] = rsqrtf(var + 1e-3f);
  }
  __syncthreads();
  float gf = g_f[t], bf = b_f[t];
#pragma unroll
  for (int k = 0; k < 8; ++k)
    fn[k][t] = (fn[k][t] - smu[k]) * srn[k] * gf + bf;
  __syncthreads();
  if (h == 0) {
    const float* wv = ws + OFF_WV;
    float s = 0.f;
#pragma unroll
    for (int m = 0; m < 8; ++m) s += fn[r][l32 + 32 * m] * wv[l32 + 32 * m];
    for (int m = 16; m >= 1; m >>= 1) s += __shfl_xor(s, m);
    if (l32 == 0) ws[OFF_VSUM + row0 + r] = s;
  }
  int matsel = t >> 7;  // wave-uniform: waves 0,1 -> Q, waves 2,3 -> K
  int col = h * 128 + (t & 127);
  const float* W = matsel ? Wk : Wq;
  float acc[8] = {0, 0, 0, 0, 0, 0, 0, 0};
#pragma unroll 2
  for (int f = 0; f < 256; f += 4) {
    float w0 = W[(f + 0) * 256 + col];
    float w1 = W[(f + 1) * 256 + col];
    float w2 = W[(f + 2) * 256 + col];
    float w3 = W[(f + 3) * 256 + col];
#pragma unroll
    for (int k = 0; k < 8; ++k) {
      v4f x = *(const v4f*)(&fn[k][f]);
      acc[k] = fmaf(x.w, w3,
               fmaf(x.z, w2, fmaf(x.y, w1, fmaf(x.x, w0, acc[k]))));
    }
  }
  if (matsel == 0) {
    float* Out = ws + OFF_Q + (size_t)row0 * 256 + col;
#pragma unroll
    for (int k = 0; k < 8; ++k) Out[k * 256] = acc[k];
  } else {
    int bb = row0 >> 9, r0b = row0 & 511;
    float* Out = ws + OFF_KT + (size_t)bb * 131072 + (size_t)col * 512 + r0b;
    v4f o0 = {acc[0], acc[1], acc[2], acc[3]};
    v4f o1 = {acc[4], acc[5], acc[6], acc[7]};
    *(v4f*)Out = o0;
    *(v4f*)(Out + 4) = o1;
  }
}

// ---------------- KB2: bias load + coalesced QK^T + softmax (R8, verified) -
__global__ __launch_bounds__(256) void kb2_attn(
    const float* __restrict__ ws, float* __restrict__ out) {
  __shared__ float Sx[4][512];
  __shared__ __align__(16) float Qs[4][256];
  __shared__ float vs[512];
  int t = threadIdx.x;
  int w = t >> 6, l = t & 63;
  int b = blockIdx.x >> 7, tile = blockIdx.x & 127;
  int rowbase = b * 512 + tile * 4;

  // stage Q rows, vsum, bias rows (all ordered by the barrier below)
#pragma unroll
  for (int k = 0; k < 4; ++k)
    Qs[k][t] = ws[OFF_Q + (size_t)(rowbase + k) * 256 + t];
  vs[t] = ws[OFF_VSUM + b * 512 + t];
  vs[t + 256] = ws[OFF_VSUM + b * 512 + 256 + t];
  const float* bb = ws + OFF_BIAS + (size_t)rowbase * 512;
#pragma unroll
  for (int rr = 0; rr < 4; ++rr) {
    Sx[rr][t] = bb[rr * 512 + t];
    Sx[rr][t + 256] = bb[rr * 512 + 256 + t];
  }
  __syncthreads();

  // ---- Phase B: QK^T/16 added into Sx. Thread t owns k-cols 2t, 2t+1 -----
  const float* Ktb = ws + OFF_KT + (size_t)b * 131072;
  float a0[4] = {0, 0, 0, 0}, a1[4] = {0, 0, 0, 0};
#pragma unroll 2
  for (int f4 = 0; f4 < 64; ++f4) {
    v4f qv0 = *(const v4f*)(&Qs[0][f4 * 4]);  // wave-uniform broadcast
    v4f qv1 = *(const v4f*)(&Qs[1][f4 * 4]);
    v4f qv2 = *(const v4f*)(&Qs[2][f4 * 4]);
    v4f qv3 = *(const v4f*)(&Qs[3][f4 * 4]);
#pragma unroll
    for (int ff = 0; ff < 4; ++ff) {
      v2f kv = *(const v2f*)(Ktb + (size_t)(f4 * 4 + ff) * 512 + 2 * t);
      a0[0] += qv0[ff] * kv.x; a1[0] += qv0[ff] * kv.y;
      a0[1] += qv1[ff] * kv.x; a1[1] += qv1[ff] * kv.y;
      a0[2] += qv2[ff] * kv.x; a1[2] += qv2[ff] * kv.y;
      a0[3] += qv3[ff] * kv.x; a1[3] += qv3[ff] * kv.y;
    }
  }
#pragma unroll
  for (int rr = 0; rr < 4; ++rr) {
    Sx[rr][2 * t]     += a0[rr] * 0.0625f;
    Sx[rr][2 * t + 1] += a1[rr] * 0.0625f;
  }
  __syncthreads();

  // ---- Phase C: wave w softmaxes row w and dots with vsum ----
  float m = -1e30f;
#pragma unroll
  for (int j = 0; j < 8; ++j) m = fmaxf(m, Sx[w][l + 64 * j]);
  for (int mm = 32; mm >= 1; mm >>= 1) m = fmaxf(m, __shfl_xor(m, mm));
  float se = 0.f, sv = 0.f;
#pragma unroll
  for (int j = 0; j < 8; ++j) {
    float ev = __expf(Sx[w][l + 64 * j] - m);
    se += ev;
    sv += ev * vs[l + 64 * j];
  }
  for (int mm = 32; mm >= 1; mm >>= 1) {
    se += __shfl_xor(se, mm);
    sv += __shfl_xor(sv, mm);
  }
  if (l == 0) out[rowbase + w] = sv / se;
}

// ---------------------------------------------------------------------------
extern "C" void kernel_launch(void* const* d_in, const int* in_sizes, int n_in,
                              void* d_out, int out_size, void* d_ws,
                              size_t ws_size, hipStream_t stream) {
  const float* F    = (const float*)d_in[0];
  const float* D    = (const float*)d_in[1];
  const float* Wq   = (const float*)d_in[2];
  const float* Wk   = (const float*)d_in[3];
  const float* Wv   = (const float*)d_in[4];
  const float* g_f  = (const float*)d_in[5];
  const float* b_f  = (const float*)d_in[6];
  const float* g_p  = (const float*)d_in[7];
  const float* b_p  = (const float*)d_in[8];
  const float* W_pt = (const float*)d_in[9];
  const float* b_pt = (const float*)d_in[10];
  const float* W_ph = (const float*)d_in[11];
  float* out = (float*)d_out;
  float* ws = (float*)d_ws;

  k0_consts<<<65, 256, 0, stream>>>(Wv, g_p, b_p, W_pt, b_pt, W_ph, ws);
  kf_proj_bias<<<4608, 256, 0, stream>>>(F, Wq, Wk, g_f, b_f, D, ws);
  kb2_attn<<<512, 256, 0, stream>>>(ws, out);
}

// Round 13
// 398.985 us; speedup vs baseline: 1.0813x; 1.0311x over previous
//
#include <hip/hip_runtime.h>
#include <cstddef>
#include <cstdint>

// Problem constants: B=4, N=512, FD=AD=256, PD=128, DP=64
// out[b,q] = softmax_k( (Q[b,q]·K[b,k] + bias[b,q,k]) / 16 ) · vsum[b,k]
//   bias[b,i,j] = rn*(dot(D[b,i,j,:],gw) - mu*sum_gw) + bconst (gw = g_p*(W_pt@W_ph))
//   vsum[b,k]   = Fn[b,k,:]·rowsum(Wv)
//
// Workspace layout (floats):
#define OFF_GW    0          // 64   : g_p * (W_pt @ W_ph)
#define OFF_WV    64         // 256  : row sums of Wv
#define OFF_SC    320        // 2    : sum_gw, bconst
#define OFF_VSUM  384        // 2048 : vsum[b,k]
#define OFF_Q     2432       // 524288 : Q [2048][256] row-major
#define OFF_KT    526720     // 524288 : K^T [4][256][512]  (Kt[b][f][k])
#define OFF_BIAS  1051008    // 1048576 : bias/16 [4][512][512] (entry-linear)

typedef float v4f __attribute__((ext_vector_type(4)));
typedef float v2f __attribute__((ext_vector_type(2)));

// ---------------- K0: constants -------------------------------------------
__global__ __launch_bounds__(256) void k0_consts(
    const float* __restrict__ Wv, const float* __restrict__ g_p,
    const float* __restrict__ b_p, const float* __restrict__ W_pt,
    const float* __restrict__ b_pt, const float* __restrict__ W_ph,
    float* __restrict__ ws) {
  int t = threadIdx.x;
  if (blockIdx.x < 64) {
    int row = blockIdx.x * 4 + (t >> 6);
    int l = t & 63;
    float s = 0.f;
#pragma unroll
    for (int j = 0; j < 4; ++j) s += Wv[row * 256 + l + 64 * j];
    for (int m = 32; m >= 1; m >>= 1) s += __shfl_xor(s, m);
    if (l == 0) ws[OFF_WV + row] = s;
  } else {
    __shared__ float wc_s[64];
    __shared__ float wph_s[128];
    if (t < 128) wph_s[t] = W_ph[t];
    __syncthreads();
    int c = t >> 2, sub = t & 3;
    float wc = 0.f;
#pragma unroll
    for (int j = 0; j < 32; ++j)
      wc += W_pt[c * 128 + sub * 32 + j] * wph_s[sub * 32 + j];
    wc += __shfl_xor(wc, 1);
    wc += __shfl_xor(wc, 2);
    if (sub == 0) {
      wc_s[c] = wc;
      ws[OFF_GW + c] = g_p[c] * wc;
    }
    __syncthreads();
    if (t == 0) {
      float sg = 0.f, bc = 0.f;
      for (int cc = 0; cc < 64; ++cc) {
        sg += g_p[cc] * wc_s[cc];
        bc += b_p[cc] * wc_s[cc];
      }
      for (int p = 0; p < 128; ++p) bc += b_pt[p] * wph_s[p];
      ws[OFF_SC] = sg;
      ws[OFF_SC + 1] = bc;
    }
  }
}

// ---------------- KF: fused [k1-projection | coalesced bias-stream] --------
// 4608 blocks x 256 threads, __launch_bounds__(256,4).
// Blocks 0..511: R11's k1 verbatim (fn aliased into the shared shmem union).
// Blocks 512..4607: bias stream, NOW WAVE-COALESCED:
//   per wave-stage (16 entries = 4 KB): 4 lane-contiguous dwordx4 (1 KB per
//   instr, 1 line-request per 64B line -> 4x fewer requests than per-thread
//   rows), XOR-swizzled LDS transpose (bank-uniform both sides), 4 lanes per
//   entry consume + shfl_xor(16,32) reduce. Register prefetch of stage s+1
//   overlaps consumption; LDS double-buffered per wave (private buffers).
__global__ __launch_bounds__(256, 4) void kf_proj_bias(
    const float* __restrict__ F, const float* __restrict__ Wq,
    const float* __restrict__ Wk, const float* __restrict__ g_f,
    const float* __restrict__ b_f, const float* __restrict__ D,
    float* __restrict__ ws) {
  __shared__ __align__(16) float shmem[8192];  // 32 KB union: fn | stage
  __shared__ float smu[8], srn[8];
  __shared__ __align__(16) float gws[64];
  int t = threadIdx.x;

  if (blockIdx.x >= 512) {
    // ---- coalesced bias path --------------------------------------------
    if (t < 64) gws[t] = ws[OFF_GW + t];
    float sum_gw = ws[OFF_SC];
    float bconst = ws[OFF_SC + 1];
    int w = t >> 6, l = t & 63;
    int el = l & 15, q = l >> 4;  // entry-local, quarter
    size_t e0 = (size_t)(blockIdx.x - 512) * 256;
    const float* Dbase = D + (e0 + w * 64) * 64;
    float* stg0 = shmem + (w * 2 + 0) * 1024;  // per-wave private dbuf
    float* stg1 = shmem + (w * 2 + 1) * 1024;
    // swizzled write float-indices for chunks c = l, l+64, l+128, l+192:
    //   idx = c*4 ^ ((c>>4 & 7) << 2)
    int wi0 = (l * 4)       ^ (((l >> 4)     & 7) << 2);
    int wi1 = (l * 4 + 256) ^ (((l >> 4) + 4 & 7) << 2);
    int wi2 = (l * 4 + 512) ^ (((l >> 4)     & 7) << 2);
    int wi3 = (l * 4 + 768) ^ (((l >> 4) + 4 & 7) << 2);
    __syncthreads();  // gws visible

    v4f A0, A1, A2, A3, B0, B1, B2, B3;
#define KF_LOAD(R0, R1, R2, R3, S)                                          \
    {                                                                       \
      const v4f* p = (const v4f*)(Dbase + (S) * 1024);                      \
      R0 = p[l]; R1 = p[l + 64]; R2 = p[l + 128]; R3 = p[l + 192];          \
    }
#define KF_STORE(BUF, R0, R1, R2, R3)                                       \
    {                                                                       \
      *(v4f*)((BUF) + wi0) = R0; *(v4f*)((BUF) + wi1) = R1;                 \
      *(v4f*)((BUF) + wi2) = R2; *(v4f*)((BUF) + wi3) = R3;                 \
    }
#define KF_CONSUME(BUF, S)                                                  \
    {                                                                       \
      float s1 = 0.f, s2 = 0.f, sw_ = 0.f;                                  \
      _Pragma("unroll")                                                     \
      for (int i = 0; i < 4; ++i) {                                         \
        int idx = (el * 64 + q * 16 + i * 4) ^ ((el & 7) << 2);             \
        v4f x = *(const v4f*)((BUF) + idx);                                 \
        v4f gv = *(const v4f*)(&gws[q * 16 + i * 4]);                       \
        s1 += x.x + x.y + x.z + x.w;                                        \
        s2 += x.x * x.x + x.y * x.y + x.z * x.z + x.w * x.w;                \
        sw_ += x.x * gv.x + x.y * gv.y + x.z * gv.z + x.w * gv.w;           \
      }                                                                     \
      s1 += __shfl_xor(s1, 16); s2 += __shfl_xor(s2, 16);                   \
      sw_ += __shfl_xor(sw_, 16);                                           \
      s1 += __shfl_xor(s1, 32); s2 += __shfl_xor(s2, 32);                   \
      sw_ += __shfl_xor(sw_, 32);                                           \
      if (q == 0) {                                                         \
        float mu = s1 * (1.f / 64.f);                                       \
        float var = s2 * (1.f / 64.f) - mu * mu;                            \
        float rn = rsqrtf(var + 1e-3f);                                     \
        ws[OFF_BIAS + e0 + w * 64 + (S) * 16 + el] =                        \
            (rn * (sw_ - mu * sum_gw) + bconst) * 0.0625f;                  \
      }                                                                     \
    }

    KF_LOAD(A0, A1, A2, A3, 0)
    KF_STORE(stg0, A0, A1, A2, A3)
    KF_LOAD(B0, B1, B2, B3, 1)
    __syncthreads();
    KF_CONSUME(stg0, 0)
    KF_STORE(stg1, B0, B1, B2, B3)
    KF_LOAD(A0, A1, A2, A3, 2)
    __syncthreads();
    KF_CONSUME(stg1, 1)
    KF_STORE(stg0, A0, A1, A2, A3)
    KF_LOAD(B0, B1, B2, B3, 3)
    __syncthreads();
    KF_CONSUME(stg0, 2)
    KF_STORE(stg1, B0, B1, B2, B3)
    __syncthreads();
    KF_CONSUME(stg1, 3)
#undef KF_LOAD
#undef KF_STORE
#undef KF_CONSUME
    return;
  }

  // ---- k1 path (R11 verbatim, fn aliased into shmem) -----------------------
  float (*fn)[260] = (float (*)[260])shmem;  // 8*260 = 2080 floats < 8192
  int g = blockIdx.x >> 1, h = blockIdx.x & 1;
  int row0 = g * 8;
  const float* Fp = F + (size_t)row0 * 256;
#pragma unroll
  for (int k = 0; k < 8; ++k) fn[k][t] = Fp[k * 256 + t];
  __syncthreads();
  int r = t >> 5, l32 = t & 31;
  float s1 = 0.f, s2 = 0.f;
#pragma unroll
  for (int m = 0; m < 8; ++m) {
    float x = fn[r][l32 + 32 * m];
    s1 += x;
    s2 += x * x;
  }
  for (int m = 16; m >= 1; m >>= 1) {
    s1 += __shfl_xor(s1, m);
    s2 += __shfl_xor(s2, m);
  }
  if (l32 == 0) {
    float mu = s1 * (1.f / 256.f);
    float var = s2 * (1.f / 256.f) - mu * mu;
    smu[r] = mu;
    srn[r] = rsqrtf(var + 1e-3f);
  }
  __syncthreads();
  float gf = g_f[t], bf = b_f[t];
#pragma unroll
  for (int k = 0; k < 8; ++k)
    fn[k][t] = (fn[k][t] - smu[k]) * srn[k] * gf + bf;
  __syncthreads();
  if (h == 0) {
    const float* wv = ws + OFF_WV;
    float s = 0.f;
#pragma unroll
    for (int m = 0; m < 8; ++m) s += fn[r][l32 + 32 * m] * wv[l32 + 32 * m];
    for (int m = 16; m >= 1; m >>= 1) s += __shfl_xor(s, m);
    if (l32 == 0) ws[OFF_VSUM + row0 + r] = s;
  }
  int matsel = t >> 7;  // wave-uniform: waves 0,1 -> Q, waves 2,3 -> K
  int col = h * 128 + (t & 127);
  const float* W = matsel ? Wk : Wq;
  float acc[8] = {0, 0, 0, 0, 0, 0, 0, 0};
#pragma unroll 2
  for (int f = 0; f < 256; f += 4) {
    float w0 = W[(f + 0) * 256 + col];
    float w1 = W[(f + 1) * 256 + col];
    float w2 = W[(f + 2) * 256 + col];
    float w3 = W[(f + 3) * 256 + col];
#pragma unroll
    for (int k = 0; k < 8; ++k) {
      v4f x = *(const v4f*)(&fn[k][f]);
      acc[k] = fmaf(x.w, w3,
               fmaf(x.z, w2, fmaf(x.y, w1, fmaf(x.x, w0, acc[k]))));
    }
  }
  if (matsel == 0) {
    float* Out = ws + OFF_Q + (size_t)row0 * 256 + col;
#pragma unroll
    for (int k = 0; k < 8; ++k) Out[k * 256] = acc[k];
  } else {
    int bb = row0 >> 9, r0b = row0 & 511;
    float* Out = ws + OFF_KT + (size_t)bb * 131072 + (size_t)col * 512 + r0b;
    v4f o0 = {acc[0], acc[1], acc[2], acc[3]};
    v4f o1 = {acc[4], acc[5], acc[6], acc[7]};
    *(v4f*)Out = o0;
    *(v4f*)(Out + 4) = o1;
  }
}

// ---------------- KB2: bias load + coalesced QK^T + softmax (R11 verbatim) -
__global__ __launch_bounds__(256) void kb2_attn(
    const float* __restrict__ ws, float* __restrict__ out) {
  __shared__ float Sx[4][512];
  __shared__ __align__(16) float Qs[4][256];
  __shared__ float vs[512];
  int t = threadIdx.x;
  int w = t >> 6, l = t & 63;
  int b = blockIdx.x >> 7, tile = blockIdx.x & 127;
  int rowbase = b * 512 + tile * 4;

  // stage Q rows, vsum, bias rows (all ordered by the barrier below)
#pragma unroll
  for (int k = 0; k < 4; ++k)
    Qs[k][t] = ws[OFF_Q + (size_t)(rowbase + k) * 256 + t];
  vs[t] = ws[OFF_VSUM + b * 512 + t];
  vs[t + 256] = ws[OFF_VSUM + b * 512 + 256 + t];
  const float* bb = ws + OFF_BIAS + (size_t)rowbase * 512;
#pragma unroll
  for (int rr = 0; rr < 4; ++rr) {
    Sx[rr][t] = bb[rr * 512 + t];
    Sx[rr][t + 256] = bb[rr * 512 + 256 + t];
  }
  __syncthreads();

  // ---- Phase B: QK^T/16 added into Sx. Thread t owns k-cols 2t, 2t+1 -----
  const float* Ktb = ws + OFF_KT + (size_t)b * 131072;
  float a0[4] = {0, 0, 0, 0}, a1[4] = {0, 0, 0, 0};
#pragma unroll 2
  for (int f4 = 0; f4 < 64; ++f4) {
    v4f qv0 = *(const v4f*)(&Qs[0][f4 * 4]);  // wave-uniform broadcast
    v4f qv1 = *(const v4f*)(&Qs[1][f4 * 4]);
    v4f qv2 = *(const v4f*)(&Qs[2][f4 * 4]);
    v4f qv3 = *(const v4f*)(&Qs[3][f4 * 4]);
#pragma unroll
    for (int ff = 0; ff < 4; ++ff) {
      v2f kv = *(const v2f*)(Ktb + (size_t)(f4 * 4 + ff) * 512 + 2 * t);
      a0[0] += qv0[ff] * kv.x; a1[0] += qv0[ff] * kv.y;
      a0[1] += qv1[ff] * kv.x; a1[1] += qv1[ff] * kv.y;
      a0[2] += qv2[ff] * kv.x; a1[2] += qv2[ff] * kv.y;
      a0[3] += qv3[ff] * kv.x; a1[3] += qv3[ff] * kv.y;
    }
  }
#pragma unroll
  for (int rr = 0; rr < 4; ++rr) {
    Sx[rr][2 * t]     += a0[rr] * 0.0625f;
    Sx[rr][2 * t + 1] += a1[rr] * 0.0625f;
  }
  __syncthreads();

  // ---- Phase C: wave w softmaxes row w and dots with vsum ----
  float m = -1e30f;
#pragma unroll
  for (int j = 0; j < 8; ++j) m = fmaxf(m, Sx[w][l + 64 * j]);
  for (int mm = 32; mm >= 1; mm >>= 1) m = fmaxf(m, __shfl_xor(m, mm));
  float se = 0.f, sv = 0.f;
#pragma unroll
  for (int j = 0; j < 8; ++j) {
    float ev = __expf(Sx[w][l + 64 * j] - m);
    se += ev;
    sv += ev * vs[l + 64 * j];
  }
  for (int mm = 32; mm >= 1; mm >>= 1) {
    se += __shfl_xor(se, mm);
    sv += __shfl_xor(sv, mm);
  }
  if (l == 0) out[rowbase + w] = sv / se;
}

// ---------------------------------------------------------------------------
extern "C" void kernel_launch(void* const* d_in, const int* in_sizes, int n_in,
                              void* d_out, int out_size, void* d_ws,
                              size_t ws_size, hipStream_t stream) {
  const float* F    = (const float*)d_in[0];
  const float* D    = (const float*)d_in[1];
  const float* Wq   = (const float*)d_in[2];
  const float* Wk   = (const float*)d_in[3];
  const float* Wv   = (const float*)d_in[4];
  const float* g_f  = (const float*)d_in[5];
  const float* b_f  = (const float*)d_in[6];
  const float* g_p  = (const float*)d_in[7];
  const float* b_p  = (const float*)d_in[8];
  const float* W_pt = (const float*)d_in[9];
  const float* b_pt = (const float*)d_in[10];
  const float* W_ph = (const float*)d_in[11];
  float* out = (float*)d_out;
  float* ws = (float*)d_ws;

  k0_consts<<<65, 256, 0, stream>>>(Wv, g_p, b_p, W_pt, b_pt, W_ph, ws);
  kf_proj_bias<<<4608, 256, 0, stream>>>(F, Wq, Wk, g_f, b_f, D, ws);
  kb2_attn<<<512, 256, 0, stream>>>(ws, out);
}